// Round 1
// baseline (6383.746 us; speedup 1.0000x reference)
//
#include <hip/hip_runtime.h>

// LabelPropagator — low-footprint VALU pipeline (6.27 MB ws).
// Inputs runtime-dtype-detected (f32 vs bf16); OUTPUT = FLOAT32 (ref out dtype).
// Shapes: S=4, c=512, kd=128, P=h*w=1024, F=16 (16384 cross keys), ce=16.
//
// R1: k_crossfuse rewritten thread-per-query (flash-style). Old version had
// 1.14e9 LDS bank-conflict cycles (43% of kernel time) from per-lane-row
// reads of 256B-stride tiles (Kl scores, Pl PV). New phase B reads K/PE at
// wave-uniform LDS addresses (broadcast, conflict-free by construction);
// Kl is f32 with a 16B XOR swizzle so phase-A writes don't serialize either.

typedef __attribute__((ext_vector_type(8))) short short8v;
typedef __attribute__((ext_vector_type(4))) float float4v;

__device__ __forceinline__ float b2f(unsigned short h){
  union { unsigned int u; float f; } c; c.u = ((unsigned int)h) << 16; return c.f;
}
__device__ __forceinline__ unsigned short f2b(float f){
  union { float f; unsigned int u; } c; c.f = f;
  unsigned int u = c.u;
  u += 0x7fffu + ((u >> 16) & 1u);     // round-to-nearest-even
  return (unsigned short)(u >> 16);
}
// flag resolve: fi==-1 forced f32, fi==-2 forced bf16, else flags[fi] (1=f32,0=bf16)
__device__ __forceinline__ int getf(const int* flags, int fi){
  return (fi == -1) ? 1 : ((fi == -2) ? 0 : flags[fi]);
}
__device__ __forceinline__ float ld1(const void* p, long i, int f32f){
  return f32f ? ((const float*)p)[i] : b2f(((const unsigned short*)p)[i]);
}
__device__ __forceinline__ void ld8(const void* p, long i, int f32f, float* o){
  if (f32f){
    float4v a = *(const float4v*)((const float*)p + i);
    float4v b = *(const float4v*)((const float*)p + i + 4);
    o[0]=a[0];o[1]=a[1];o[2]=a[2];o[3]=a[3];o[4]=b[0];o[5]=b[1];o[6]=b[2];o[7]=b[3];
  } else {
    short8v v = *(const short8v*)((const unsigned short*)p + i);
    #pragma unroll
    for (int j=0;j<8;j++) o[j] = b2f((unsigned short)v[j]);
  }
}

// ---------------------------------------------------------------------------
// k_detect: flags[i]=1 if input i is f32 (bf16-exponent>=200 rate > 6.25% over
// first min(n,8192) uint16s; f32-as-bf16 gives ~11%, real bf16 data ~0%).
// ---------------------------------------------------------------------------
__global__ __launch_bounds__(256) void k_detect(
    const void* p0, const void* p1, const void* p2, const void* p3,
    const void* p4, const void* p5, const void* p6,
    int n0, int n1, int n2, int n3, int n4, int n5, int n6,
    int* __restrict__ flags)
{
  const int i = blockIdx.x, t = threadIdx.x;
  const void* ps[7] = {p0,p1,p2,p3,p4,p5,p6};
  int ns[7] = {n0,n1,n2,n3,n4,n5,n6};
  const unsigned short* u = (const unsigned short*)ps[i];
  int n = ns[i]; if (n > 8192) n = 8192;
  int cnt = 0;
  for (int k=t; k<n; k+=256){
    int e = (u[k] >> 7) & 0xFF;
    cnt += (e >= 200) ? 1 : 0;
  }
  __shared__ int red[256];
  red[t] = cnt; __syncthreads();
  for (int off=128; off>0; off>>=1){
    if (t < off) red[t] += red[t+off];
    __syncthreads();
  }
  if (t == 0) flags[i] = (red[0]*16 > n) ? 1 : 0;
}

// ---------------------------------------------------------------------------
// k_proj_g: Out[s][n][128] (bf16) = l2norm(X_token(n) @ W^T + b)
// X layout: [(f*4+s)*512 + ch]*1024 + p, f=n>>10, p=n&1023. Block=128 (d).
// ---------------------------------------------------------------------------
__global__ __launch_bounds__(128) void k_proj_g(
    const void* __restrict__ Xv, int xfi,
    const void* __restrict__ Wv, int wfi,
    const void* __restrict__ Bv, int bfi,
    const int* __restrict__ flags,
    unsigned short* __restrict__ Out, int Ntot)
{
  const int n = blockIdx.x, s = blockIdx.y, d = threadIdx.x;
  const int xf = getf(flags,xfi), wf = getf(flags,wfi), bf = getf(flags,bfi);
  const int f = n >> 10, p = n & 1023;
  const long base = ((long)(f*4 + s) * 512) * 1024 + p;
  float acc = ld1(Bv, d, bf);
  const long wbase = (long)d * 512;
  float wv[8];
  for (int ch=0; ch<512; ch+=8){
    ld8(Wv, wbase + ch, wf, wv);
    #pragma unroll
    for (int j=0;j<8;j++)
      acc += ld1(Xv, base + (long)(ch+j)*1024, xf) * wv[j];
  }
  __shared__ float red[128];
  red[d] = acc*acc;
  __syncthreads();
  for (int off=64; off>0; off>>=1){
    if (d < off) red[d] += red[d+off];
    __syncthreads();
  }
  float r = 1.f / fmaxf(sqrtf(fmaxf(red[0], 0.f)), 1e-12f);
  Out[((long)s*Ntot + n)*128 + d] = f2b(acc * r);
}

// ---------------------------------------------------------------------------
// k_self: per (s,n): fixed-shift softmax over 1024 keys (exp(30d-30), diag
// key => Z>=~1; identical to ref softmax), PV over 512 ch, residual add.
// Y[s][ch][n] (bf16) = tgt + attn.
// ---------------------------------------------------------------------------
__global__ __launch_bounds__(256) void k_self(
    const unsigned short* __restrict__ wq,   // [s][1024][128] bf16 (ws)
    const void* __restrict__ tgt,            // [s][512][1024] flagged
    const int* __restrict__ flags,
    unsigned short* __restrict__ Y)          // [s][512][1024] bf16
{
  const int n = blockIdx.x, s = blockIdx.y, t = threadIdx.x;
  const int tf = flags[0];
  __shared__ float qrow[128];
  __shared__ float ps[1024];
  __shared__ float zred[256];
  if (t < 128) qrow[t] = b2f(wq[((long)s*1024 + n)*128 + t]);
  __syncthreads();
  float zp = 0.f;
  #pragma unroll
  for (int kb=0; kb<4; kb++){
    int k = t + kb*256;
    const unsigned short* kr = wq + ((long)s*1024 + k)*128;
    float dot = 0.f;
    for (int d2=0; d2<128; d2+=8){
      short8v kv = *(const short8v*)(kr + d2);
      #pragma unroll
      for (int j=0;j<8;j++) dot += qrow[d2+j] * b2f((unsigned short)kv[j]);
    }
    float pv = __expf(30.f*dot - 30.f);
    ps[k] = pv; zp += pv;
  }
  zred[t] = zp; __syncthreads();
  for (int off=128; off>0; off>>=1){
    if (t < off) zred[t] += zred[t+off];
    __syncthreads();
  }
  float iz = 1.f / fmaxf(zred[0], 1e-30f);
  float vv[8];
  #pragma unroll
  for (int cb=0; cb<2; cb++){
    int ch = t + cb*256;
    const long vrbase = ((long)s*512 + ch)*1024;
    float acc = 0.f;
    for (int k=0; k<1024; k+=8){
      ld8(tgt, vrbase + k, tf, vv);
      #pragma unroll
      for (int j=0;j<8;j++) acc += ps[k+j] * vv[j];
    }
    Y[vrbase + n] = f2b(ld1(tgt, vrbase + n, tf) + acc*iz);
  }
}

// ---------------------------------------------------------------------------
// k_inorm: in-place InstanceNorm (biased var, eps 1e-5) over 1024 tokens.
// ---------------------------------------------------------------------------
__global__ __launch_bounds__(256) void k_inorm(unsigned short* __restrict__ Y)
{
  const int ch = blockIdx.x, s = blockIdx.y, t = threadIdx.x;
  unsigned short* row = Y + ((long)s*512 + ch)*1024;
  float v[4]; float sum=0.f, ss=0.f;
  #pragma unroll
  for (int i=0;i<4;i++){ v[i]=b2f(row[t+256*i]); sum+=v[i]; ss+=v[i]*v[i]; }
  __shared__ float r1[256], r2[256];
  r1[t]=sum; r2[t]=ss; __syncthreads();
  for (int off=128; off>0; off>>=1){
    if (t<off){ r1[t]+=r1[t+off]; r2[t]+=r2[t+off]; }
    __syncthreads();
  }
  float mean = r1[0]*(1.f/1024.f);
  float var  = fmaxf(r2[0]*(1.f/1024.f) - mean*mean, 0.f);
  float rstd = rsqrtf(var + 1e-5f);
  #pragma unroll
  for (int i=0;i<4;i++) row[t+256*i] = f2b((v[i]-mean)*rstd);
}

// ---------------------------------------------------------------------------
// k_crossfuse (R1): block = (key-chunk c, s); chunk = 128 consecutive keys of
// one frame (f=c>>3, p0=(c&7)*128).
// Phase A: project + l2norm the chunk's 128 keys into LDS as f32 [128][128],
//          16B-XOR-swizzled per row (byte ^= (key&7)<<4) so the per-lane-row
//          writes don't bank-serialize. PE tile staged transposed [k][16e].
// Phase B: thread-per-query. Each lane owns query q = qi*256 + t (qi=0..3):
//          qrow f32 in regs, loops all 128 keys reading Kl/PEl at
//          WAVE-UNIFORM addresses (pure broadcast -> zero bank conflicts),
//          accumulates O[16] + Z in regs, one atomicAdd batch per query.
// Fixed-shift exp(30d-30) => partials from the 128 chunks sum in OZ.
// ---------------------------------------------------------------------------
__global__ __launch_bounds__(256, 2) void k_crossfuse(
    const unsigned short* __restrict__ wqC,  // [s][1024][128] bf16 (ws)
    const void* __restrict__ mem,            // [(f*4+s)*512+ch][1024] flagged
    const void* __restrict__ pe,             // [(f*4+s)*16+e][1024] flagged
    const void* __restrict__ Wv,             // [128][512] flagged
    const void* __restrict__ Bv,             // [128] flagged
    const int* __restrict__ flags,
    float* __restrict__ OZ)                  // [s][1024][17] f32 (pre-zeroed)
{
  const int c = blockIdx.x, s = blockIdx.y, t = threadIdx.x;
  const int f = c >> 3, p0 = (c & 7) * 128;
  const int mf = flags[1], pf = flags[2], wf = flags[5], bf = flags[6];

  __shared__ float Kl[128*128];     // 64 KB: [key][d] f32, row-XOR-swizzled
  __shared__ float PEl[128*16];     //  8 KB: [key][e]  f32
  __shared__ float ssred[256];

  // ---- Phase A: project + normalize 128 keys (thread = (key kk, dim-half hh))
  const int kk = t & 127, hh = t >> 7;
  {
    float acc[64];
    #pragma unroll
    for (int d=0; d<64; d++) acc[d] = 0.f;
    const long xcol = ((long)(f*4 + s) * 512) * 1024 + p0 + kk;
    for (int ch=0; ch<512; ch+=8){
      float xv[8];
      #pragma unroll
      for (int j=0;j<8;j++) xv[j] = ld1(mem, xcol + (long)(ch+j)*1024, mf);
      for (int d=0; d<64; d++){
        float wv8[8];
        ld8(Wv, (long)(hh*64 + d)*512 + ch, wf, wv8);
        #pragma unroll
        for (int j=0;j<8;j++) acc[d] += xv[j]*wv8[j];
      }
    }
    float ss = 0.f;
    #pragma unroll
    for (int d=0; d<64; d++){
      acc[d] += ld1(Bv, hh*64 + d, bf);
      ss += acc[d]*acc[d];
    }
    ssred[kk*2 + hh] = ss;
    __syncthreads();
    float inv = 1.f / fmaxf(sqrtf(fmaxf(ssred[kk*2] + ssred[kk*2+1], 0.f)), 1e-12f);
    // swizzled f32 stores: 16 x ds_write_b128, spread over 8 bank-groups
    char* krow = (char*)Kl + kk*512;
    const int xk = (kk & 7) << 4;
    #pragma unroll
    for (int d=0; d<64; d+=4){
      float4v v4 = { acc[d]*inv, acc[d+1]*inv, acc[d+2]*inv, acc[d+3]*inv };
      *(float4v*)(krow + ((hh*256 + d*4) ^ xk)) = v4;
    }
  }
  // ---- Phase A2: pos_enc tile, TRANSPOSED [key][e] for b128 uniform reads
  #pragma unroll
  for (int i=0;i<8;i++){
    int idx = t*8 + i;            // 0..2047
    int k2 = idx >> 4, e = idx & 15;
    PEl[k2*16 + e] = ld1(pe, ((long)((f*4 + s)*16 + e))*1024 + p0 + k2, pf);
  }
  __syncthreads();

  // ---- Phase B: thread-per-query over all 1024 queries
  const char* Klb = (const char*)Kl;
  for (int qi=0; qi<4; ++qi){
    const int q = qi*256 + t;
    // load this lane's query row (bf16 -> f32 regs)
    float qr[128];
    const unsigned short* qp = wqC + ((long)s*1024 + q)*128;
    #pragma unroll
    for (int d=0; d<128; d+=8){
      short8v v = *(const short8v*)(qp + d);
      #pragma unroll
      for (int j=0;j<8;j++) qr[d+j] = b2f((unsigned short)v[j]);
    }
    float O[16];
    #pragma unroll
    for (int e=0; e<16; e++) O[e] = 0.f;
    float z = 0.f;

    for (int k=0; k<128; ++k){
      const char* krow = Klb + k*512;
      const int xk = (k & 7) << 4;
      float4v dv = {0.f, 0.f, 0.f, 0.f};
      #pragma unroll
      for (int d=0; d<128; d+=4){
        float4v kv = *(const float4v*)(krow + ((d*4) ^ xk));   // uniform: broadcast
        dv[0] += qr[d+0]*kv[0];
        dv[1] += qr[d+1]*kv[1];
        dv[2] += qr[d+2]*kv[2];
        dv[3] += qr[d+3]*kv[3];
      }
      float dot = (dv[0]+dv[1]) + (dv[2]+dv[3]);
      float p = __expf(30.f*dot - 30.f);
      z += p;
      const float4v* per = (const float4v*)&PEl[k*16];         // uniform: broadcast
      #pragma unroll
      for (int e4=0; e4<4; ++e4){
        float4v pv = per[e4];
        O[e4*4+0] += p*pv[0];
        O[e4*4+1] += p*pv[1];
        O[e4*4+2] += p*pv[2];
        O[e4*4+3] += p*pv[3];
      }
    }

    float* oz = OZ + ((long)s*1024 + q)*17;
    #pragma unroll
    for (int e=0; e<16; e++) atomicAdd(&oz[e], O[e]);
    atomicAdd(&oz[16], z);
  }
}

// ---------------------------------------------------------------------------
// k_final: out (FLOAT32) = sigmoid(O/Z); diagnostic if ws too small.
// out[i], i = ((s*16+e)<<10)+n  (s=i>>14, e=(i>>10)&15, n=i&1023).
// ---------------------------------------------------------------------------
__global__ __launch_bounds__(256) void k_final(
    const float* __restrict__ OZ, float* __restrict__ out,
    const int* __restrict__ flags, int sane, int detect_ok, int ws_mb)
{
  const int i = blockIdx.x*256 + threadIdx.x;   // 0..65535
  if (!sane){
    float v = 0.5f;
    if (i == 0){
      int F = 0;
      if (detect_ok)
        F = flags[0]*16 + flags[1]*8 + flags[2]*4 + flags[3]*2 + flags[5];
      int wm = ws_mb > 99 ? 99 : ws_mb;
      v = ldexpf(1.f + (float)wm*(1.f/128.f), 40 + F);
    }
    out[i] = v;
    return;
  }
  const int s = i >> 14, e = (i >> 10) & 15, n = i & 1023;
  const float* oz = OZ + ((long)s*1024 + n)*17;
  float x = oz[e] / fmaxf(oz[16], 1e-30f);
  out[i] = 1.f / (1.f + __expf(-x));
}

// ---------------------------------------------------------------------------
extern "C" void kernel_launch(void* const* d_in, const int* in_sizes, int n_in,
                              void* d_out, int out_size, void* d_ws, size_t ws_size,
                              hipStream_t stream)
{
  const void* tgt = d_in[0];
  const void* mem = d_in[1];
  const void* pe  = d_in[2];
  const void* wks = d_in[3];
  const void* bks = d_in[4];
  const void* wkc = d_in[5];
  const void* bkc = d_in[6];
  float* out = (float*)d_out;   // [4][16][1024] FLOAT32 (reference output dtype)

  char* w = (char*)d_ws;
  int*            flags = (int*)w;          w += 256;
  unsigned short* wqS = (unsigned short*)w; w += (size_t)4*1024*128*2;   // 1 MB
  unsigned short* wqC = (unsigned short*)w; w += (size_t)4*1024*128*2;   // 1 MB
  unsigned short* Y   = (unsigned short*)w; w += (size_t)4*512*1024*2;   // 4 MB
  float*          OZ  = (float*)w;          w += (size_t)4*1024*17*4;    // 272 KB
  const size_t NEED = (size_t)(w - (char*)d_ws);

  const int detect_ok = ws_size >= 4096;
  const int sane = ws_size >= NEED;

  if (detect_ok)
    hipLaunchKernelGGL(k_detect, dim3(7), dim3(256), 0, stream,
                       tgt, mem, pe, wks, bks, wkc, bkc,
                       in_sizes[0], in_sizes[1], in_sizes[2], in_sizes[3],
                       in_sizes[4], in_sizes[5], in_sizes[6], flags);
  if (sane){
    hipMemsetAsync(OZ, 0, (size_t)4*1024*17*4, stream);
    hipLaunchKernelGGL(k_proj_g, dim3(1024,4), dim3(128), 0, stream,
                       tgt, 0, wks, 3, bks, 4, flags, wqS, 1024);
    hipLaunchKernelGGL(k_self, dim3(1024,4), dim3(256), 0, stream,
                       wqS, tgt, flags, Y);
    hipLaunchKernelGGL(k_inorm, dim3(512,4), dim3(256), 0, stream, Y);
    hipLaunchKernelGGL(k_proj_g, dim3(1024,4), dim3(128), 0, stream,
                       (const void*)Y, -2, wkc, 5, bkc, 6, flags, wqC, 1024);
    hipLaunchKernelGGL(k_crossfuse, dim3(128,4), dim3(256), 0, stream,
                       wqC, mem, pe, wkc, bkc, flags, OZ);
  }
  hipLaunchKernelGGL(k_final, dim3(256), dim3(256), 0, stream,
                     OZ, out, flags, sane, detect_ok, (int)(ws_size >> 20));
}

// Round 2
// 6376.927 us; speedup vs baseline: 1.0011x; 1.0011x over previous
//
#include <hip/hip_runtime.h>

// LabelPropagator — low-footprint VALU pipeline (6.27 MB ws).
// Inputs runtime-dtype-detected (f32 vs bf16); OUTPUT = FLOAT32 (ref out dtype).
// Shapes: S=4, c=512, kd=128, P=h*w=1024, F=16 (16384 cross keys), ce=16.
//
// R1: k_crossfuse thread-per-query; uniform (broadcast) LDS reads killed the
//     1.14e9 bank-conflict cycles (verified: -> 2.3e5).
// R2: R1 spilled qr[128] f32 (VGPR capped at 128 -> 17.6 GB scratch traffic,
//     FETCH 5.7GB/WRITE 11.4GB). Phase B now keeps the query row bf16-PACKED
//     in 64 u32 regs and unpacks inline (1 shl / 1 and per element): ~100
//     VGPRs live -> no spills, 2 blocks/CU.

typedef __attribute__((ext_vector_type(8))) short short8v;
typedef __attribute__((ext_vector_type(4))) float float4v;
typedef __attribute__((ext_vector_type(4))) unsigned int uint4v;

__device__ __forceinline__ float b2f(unsigned short h){
  union { unsigned int u; float f; } c; c.u = ((unsigned int)h) << 16; return c.f;
}
__device__ __forceinline__ unsigned short f2b(float f){
  union { float f; unsigned int u; } c; c.f = f;
  unsigned int u = c.u;
  u += 0x7fffu + ((u >> 16) & 1u);     // round-to-nearest-even
  return (unsigned short)(u >> 16);
}
// packed-bf16 unpack: low element (bits 15:0) and high element (bits 31:16)
__device__ __forceinline__ float bl(unsigned int u){
  union { unsigned int x; float f; } c; c.x = u << 16; return c.f;
}
__device__ __forceinline__ float bh(unsigned int u){
  union { unsigned int x; float f; } c; c.x = u & 0xffff0000u; return c.f;
}
// flag resolve: fi==-1 forced f32, fi==-2 forced bf16, else flags[fi] (1=f32,0=bf16)
__device__ __forceinline__ int getf(const int* flags, int fi){
  return (fi == -1) ? 1 : ((fi == -2) ? 0 : flags[fi]);
}
__device__ __forceinline__ float ld1(const void* p, long i, int f32f){
  return f32f ? ((const float*)p)[i] : b2f(((const unsigned short*)p)[i]);
}
__device__ __forceinline__ void ld8(const void* p, long i, int f32f, float* o){
  if (f32f){
    float4v a = *(const float4v*)((const float*)p + i);
    float4v b = *(const float4v*)((const float*)p + i + 4);
    o[0]=a[0];o[1]=a[1];o[2]=a[2];o[3]=a[3];o[4]=b[0];o[5]=b[1];o[6]=b[2];o[7]=b[3];
  } else {
    short8v v = *(const short8v*)((const unsigned short*)p + i);
    #pragma unroll
    for (int j=0;j<8;j++) o[j] = b2f((unsigned short)v[j]);
  }
}

// ---------------------------------------------------------------------------
// k_detect: flags[i]=1 if input i is f32 (bf16-exponent>=200 rate > 6.25% over
// first min(n,8192) uint16s; f32-as-bf16 gives ~11%, real bf16 data ~0%).
// ---------------------------------------------------------------------------
__global__ __launch_bounds__(256) void k_detect(
    const void* p0, const void* p1, const void* p2, const void* p3,
    const void* p4, const void* p5, const void* p6,
    int n0, int n1, int n2, int n3, int n4, int n5, int n6,
    int* __restrict__ flags)
{
  const int i = blockIdx.x, t = threadIdx.x;
  const void* ps[7] = {p0,p1,p2,p3,p4,p5,p6};
  int ns[7] = {n0,n1,n2,n3,n4,n5,n6};
  const unsigned short* u = (const unsigned short*)ps[i];
  int n = ns[i]; if (n > 8192) n = 8192;
  int cnt = 0;
  for (int k=t; k<n; k+=256){
    int e = (u[k] >> 7) & 0xFF;
    cnt += (e >= 200) ? 1 : 0;
  }
  __shared__ int red[256];
  red[t] = cnt; __syncthreads();
  for (int off=128; off>0; off>>=1){
    if (t < off) red[t] += red[t+off];
    __syncthreads();
  }
  if (t == 0) flags[i] = (red[0]*16 > n) ? 1 : 0;
}

// ---------------------------------------------------------------------------
// k_proj_g: Out[s][n][128] (bf16) = l2norm(X_token(n) @ W^T + b)
// X layout: [(f*4+s)*512 + ch]*1024 + p, f=n>>10, p=n&1023. Block=128 (d).
// ---------------------------------------------------------------------------
__global__ __launch_bounds__(128) void k_proj_g(
    const void* __restrict__ Xv, int xfi,
    const void* __restrict__ Wv, int wfi,
    const void* __restrict__ Bv, int bfi,
    const int* __restrict__ flags,
    unsigned short* __restrict__ Out, int Ntot)
{
  const int n = blockIdx.x, s = blockIdx.y, d = threadIdx.x;
  const int xf = getf(flags,xfi), wf = getf(flags,wfi), bf = getf(flags,bfi);
  const int f = n >> 10, p = n & 1023;
  const long base = ((long)(f*4 + s) * 512) * 1024 + p;
  float acc = ld1(Bv, d, bf);
  const long wbase = (long)d * 512;
  float wv[8];
  for (int ch=0; ch<512; ch+=8){
    ld8(Wv, wbase + ch, wf, wv);
    #pragma unroll
    for (int j=0;j<8;j++)
      acc += ld1(Xv, base + (long)(ch+j)*1024, xf) * wv[j];
  }
  __shared__ float red[128];
  red[d] = acc*acc;
  __syncthreads();
  for (int off=64; off>0; off>>=1){
    if (d < off) red[d] += red[d+off];
    __syncthreads();
  }
  float r = 1.f / fmaxf(sqrtf(fmaxf(red[0], 0.f)), 1e-12f);
  Out[((long)s*Ntot + n)*128 + d] = f2b(acc * r);
}

// ---------------------------------------------------------------------------
// k_self: per (s,n): fixed-shift softmax over 1024 keys (exp(30d-30), diag
// key => Z>=~1; identical to ref softmax), PV over 512 ch, residual add.
// Y[s][ch][n] (bf16) = tgt + attn.
// ---------------------------------------------------------------------------
__global__ __launch_bounds__(256) void k_self(
    const unsigned short* __restrict__ wq,   // [s][1024][128] bf16 (ws)
    const void* __restrict__ tgt,            // [s][512][1024] flagged
    const int* __restrict__ flags,
    unsigned short* __restrict__ Y)          // [s][512][1024] bf16
{
  const int n = blockIdx.x, s = blockIdx.y, t = threadIdx.x;
  const int tf = flags[0];
  __shared__ float qrow[128];
  __shared__ float ps[1024];
  __shared__ float zred[256];
  if (t < 128) qrow[t] = b2f(wq[((long)s*1024 + n)*128 + t]);
  __syncthreads();
  float zp = 0.f;
  #pragma unroll
  for (int kb=0; kb<4; kb++){
    int k = t + kb*256;
    const unsigned short* kr = wq + ((long)s*1024 + k)*128;
    float dot = 0.f;
    for (int d2=0; d2<128; d2+=8){
      short8v kv = *(const short8v*)(kr + d2);
      #pragma unroll
      for (int j=0;j<8;j++) dot += qrow[d2+j] * b2f((unsigned short)kv[j]);
    }
    float pv = __expf(30.f*dot - 30.f);
    ps[k] = pv; zp += pv;
  }
  zred[t] = zp; __syncthreads();
  for (int off=128; off>0; off>>=1){
    if (t < off) zred[t] += zred[t+off];
    __syncthreads();
  }
  float iz = 1.f / fmaxf(zred[0], 1e-30f);
  float vv[8];
  #pragma unroll
  for (int cb=0; cb<2; cb++){
    int ch = t + cb*256;
    const long vrbase = ((long)s*512 + ch)*1024;
    float acc = 0.f;
    for (int k=0; k<1024; k+=8){
      ld8(tgt, vrbase + k, tf, vv);
      #pragma unroll
      for (int j=0;j<8;j++) acc += ps[k+j] * vv[j];
    }
    Y[vrbase + n] = f2b(ld1(tgt, vrbase + n, tf) + acc*iz);
  }
}

// ---------------------------------------------------------------------------
// k_inorm: in-place InstanceNorm (biased var, eps 1e-5) over 1024 tokens.
// ---------------------------------------------------------------------------
__global__ __launch_bounds__(256) void k_inorm(unsigned short* __restrict__ Y)
{
  const int ch = blockIdx.x, s = blockIdx.y, t = threadIdx.x;
  unsigned short* row = Y + ((long)s*512 + ch)*1024;
  float v[4]; float sum=0.f, ss=0.f;
  #pragma unroll
  for (int i=0;i<4;i++){ v[i]=b2f(row[t+256*i]); sum+=v[i]; ss+=v[i]*v[i]; }
  __shared__ float r1[256], r2[256];
  r1[t]=sum; r2[t]=ss; __syncthreads();
  for (int off=128; off>0; off>>=1){
    if (t<off){ r1[t]+=r1[t+off]; r2[t]+=r2[t+off]; }
    __syncthreads();
  }
  float mean = r1[0]*(1.f/1024.f);
  float var  = fmaxf(r2[0]*(1.f/1024.f) - mean*mean, 0.f);
  float rstd = rsqrtf(var + 1e-5f);
  #pragma unroll
  for (int i=0;i<4;i++) row[t+256*i] = f2b((v[i]-mean)*rstd);
}

// ---------------------------------------------------------------------------
// k_crossfuse (R2): block = (key-chunk c, s); chunk = 128 consecutive keys of
// one frame (f=c>>3, p0=(c&7)*128).
// Phase A: project + l2norm the chunk's 128 keys into LDS as f32 [128][128],
//          16B-XOR-swizzled per row (byte ^= (key&7)<<4) so the per-lane-row
//          writes don't bank-serialize. PE tile staged transposed [k][16e].
// Phase B: thread-per-query. Each lane owns query q = qi*256 + t (qi=0..3):
//          q row held bf16-PACKED in 64 u32 regs (no spill; unpack inline),
//          loops all 128 keys reading Kl/PEl at WAVE-UNIFORM addresses
//          (pure broadcast -> zero bank conflicts), accumulates O[16] + Z in
//          regs, one atomicAdd batch per query.
// Fixed-shift exp(30d-30) => partials from the 128 chunks sum in OZ.
// ---------------------------------------------------------------------------
__global__ __launch_bounds__(256, 2) void k_crossfuse(
    const unsigned short* __restrict__ wqC,  // [s][1024][128] bf16 (ws)
    const void* __restrict__ mem,            // [(f*4+s)*512+ch][1024] flagged
    const void* __restrict__ pe,             // [(f*4+s)*16+e][1024] flagged
    const void* __restrict__ Wv,             // [128][512] flagged
    const void* __restrict__ Bv,             // [128] flagged
    const int* __restrict__ flags,
    float* __restrict__ OZ)                  // [s][1024][17] f32 (pre-zeroed)
{
  const int c = blockIdx.x, s = blockIdx.y, t = threadIdx.x;
  const int f = c >> 3, p0 = (c & 7) * 128;
  const int mf = flags[1], pf = flags[2], wf = flags[5], bf = flags[6];

  __shared__ float Kl[128*128];     // 64 KB: [key][d] f32, row-XOR-swizzled
  __shared__ float PEl[128*16];     //  8 KB: [key][e]  f32
  __shared__ float ssred[256];

  // ---- Phase A: project + normalize 128 keys (thread = (key kk, dim-half hh))
  const int kk = t & 127, hh = t >> 7;
  {
    float acc[64];
    #pragma unroll
    for (int d=0; d<64; d++) acc[d] = 0.f;
    const long xcol = ((long)(f*4 + s) * 512) * 1024 + p0 + kk;
    for (int ch=0; ch<512; ch+=8){
      float xv[8];
      #pragma unroll
      for (int j=0;j<8;j++) xv[j] = ld1(mem, xcol + (long)(ch+j)*1024, mf);
      for (int d=0; d<64; d++){
        float wv8[8];
        ld8(Wv, (long)(hh*64 + d)*512 + ch, wf, wv8);
        #pragma unroll
        for (int j=0;j<8;j++) acc[d] += xv[j]*wv8[j];
      }
    }
    float ss = 0.f;
    #pragma unroll
    for (int d=0; d<64; d++){
      acc[d] += ld1(Bv, hh*64 + d, bf);
      ss += acc[d]*acc[d];
    }
    ssred[kk*2 + hh] = ss;
    __syncthreads();
    float inv = 1.f / fmaxf(sqrtf(fmaxf(ssred[kk*2] + ssred[kk*2+1], 0.f)), 1e-12f);
    // swizzled f32 stores: 16 x ds_write_b128, spread over 8 bank-groups
    char* krow = (char*)Kl + kk*512;
    const int xk = (kk & 7) << 4;
    #pragma unroll
    for (int d=0; d<64; d+=4){
      float4v v4 = { acc[d]*inv, acc[d+1]*inv, acc[d+2]*inv, acc[d+3]*inv };
      *(float4v*)(krow + ((hh*256 + d*4) ^ xk)) = v4;
    }
  }
  // ---- Phase A2: pos_enc tile, TRANSPOSED [key][e] for b128 uniform reads
  #pragma unroll
  for (int i=0;i<8;i++){
    int idx = t*8 + i;            // 0..2047
    int k2 = idx >> 4, e = idx & 15;
    PEl[k2*16 + e] = ld1(pe, ((long)((f*4 + s)*16 + e))*1024 + p0 + k2, pf);
  }
  __syncthreads();

  // ---- Phase B: thread-per-query over all 1024 queries
  const char* Klb = (const char*)Kl;
  for (int qi=0; qi<4; ++qi){
    const int q = qi*256 + t;
    // load this lane's query row bf16-PACKED into 64 u32 regs (16B loads)
    unsigned int qp_[64];
    const unsigned int* qpw = (const unsigned int*)(wqC + ((long)s*1024 + q)*128);
    #pragma unroll
    for (int d=0; d<64; d+=4){
      uint4v v = *(const uint4v*)(qpw + d);
      qp_[d]=v[0]; qp_[d+1]=v[1]; qp_[d+2]=v[2]; qp_[d+3]=v[3];
    }
    float O[16];
    #pragma unroll
    for (int e=0; e<16; e++) O[e] = 0.f;
    float z = 0.f;

    for (int k=0; k<128; ++k){
      const char* krow = Klb + k*512;
      const int xk = (k & 7) << 4;
      float dv0=0.f, dv1=0.f, dv2=0.f, dv3=0.f;
      #pragma unroll
      for (int d4=0; d4<32; ++d4){
        float4v kv = *(const float4v*)(krow + ((d4*16) ^ xk));  // uniform: broadcast
        unsigned int a = qp_[2*d4], b = qp_[2*d4+1];
        dv0 += bl(a)*kv[0];
        dv1 += bh(a)*kv[1];
        dv2 += bl(b)*kv[2];
        dv3 += bh(b)*kv[3];
      }
      float dot = (dv0+dv1) + (dv2+dv3);
      float p = __expf(30.f*dot - 30.f);
      z += p;
      const float4v* per = (const float4v*)&PEl[k*16];          // uniform: broadcast
      #pragma unroll
      for (int e4=0; e4<4; ++e4){
        float4v pv = per[e4];
        O[e4*4+0] += p*pv[0];
        O[e4*4+1] += p*pv[1];
        O[e4*4+2] += p*pv[2];
        O[e4*4+3] += p*pv[3];
      }
    }

    float* oz = OZ + ((long)s*1024 + q)*17;
    #pragma unroll
    for (int e=0; e<16; e++) atomicAdd(&oz[e], O[e]);
    atomicAdd(&oz[16], z);
  }
}

// ---------------------------------------------------------------------------
// k_final: out (FLOAT32) = sigmoid(O/Z); diagnostic if ws too small.
// out[i], i = ((s*16+e)<<10)+n  (s=i>>14, e=(i>>10)&15, n=i&1023).
// ---------------------------------------------------------------------------
__global__ __launch_bounds__(256) void k_final(
    const float* __restrict__ OZ, float* __restrict__ out,
    const int* __restrict__ flags, int sane, int detect_ok, int ws_mb)
{
  const int i = blockIdx.x*256 + threadIdx.x;   // 0..65535
  if (!sane){
    float v = 0.5f;
    if (i == 0){
      int F = 0;
      if (detect_ok)
        F = flags[0]*16 + flags[1]*8 + flags[2]*4 + flags[3]*2 + flags[5];
      int wm = ws_mb > 99 ? 99 : ws_mb;
      v = ldexpf(1.f + (float)wm*(1.f/128.f), 40 + F);
    }
    out[i] = v;
    return;
  }
  const int s = i >> 14, e = (i >> 10) & 15, n = i & 1023;
  const float* oz = OZ + ((long)s*1024 + n)*17;
  float x = oz[e] / fmaxf(oz[16], 1e-30f);
  out[i] = 1.f / (1.f + __expf(-x));
}

// ---------------------------------------------------------------------------
extern "C" void kernel_launch(void* const* d_in, const int* in_sizes, int n_in,
                              void* d_out, int out_size, void* d_ws, size_t ws_size,
                              hipStream_t stream)
{
  const void* tgt = d_in[0];
  const void* mem = d_in[1];
  const void* pe  = d_in[2];
  const void* wks = d_in[3];
  const void* bks = d_in[4];
  const void* wkc = d_in[5];
  const void* bkc = d_in[6];
  float* out = (float*)d_out;   // [4][16][1024] FLOAT32 (reference output dtype)

  char* w = (char*)d_ws;
  int*            flags = (int*)w;          w += 256;
  unsigned short* wqS = (unsigned short*)w; w += (size_t)4*1024*128*2;   // 1 MB
  unsigned short* wqC = (unsigned short*)w; w += (size_t)4*1024*128*2;   // 1 MB
  unsigned short* Y   = (unsigned short*)w; w += (size_t)4*512*1024*2;   // 4 MB
  float*          OZ  = (float*)w;          w += (size_t)4*1024*17*4;    // 272 KB
  const size_t NEED = (size_t)(w - (char*)d_ws);

  const int detect_ok = ws_size >= 4096;
  const int sane = ws_size >= NEED;

  if (detect_ok)
    hipLaunchKernelGGL(k_detect, dim3(7), dim3(256), 0, stream,
                       tgt, mem, pe, wks, bks, wkc, bkc,
                       in_sizes[0], in_sizes[1], in_sizes[2], in_sizes[3],
                       in_sizes[4], in_sizes[5], in_sizes[6], flags);
  if (sane){
    hipMemsetAsync(OZ, 0, (size_t)4*1024*17*4, stream);
    hipLaunchKernelGGL(k_proj_g, dim3(1024,4), dim3(128), 0, stream,
                       tgt, 0, wks, 3, bks, 4, flags, wqS, 1024);
    hipLaunchKernelGGL(k_self, dim3(1024,4), dim3(256), 0, stream,
                       wqS, tgt, flags, Y);
    hipLaunchKernelGGL(k_inorm, dim3(512,4), dim3(256), 0, stream, Y);
    hipLaunchKernelGGL(k_proj_g, dim3(1024,4), dim3(128), 0, stream,
                       (const void*)Y, -2, wkc, 5, bkc, 6, flags, wqC, 1024);
    hipLaunchKernelGGL(k_crossfuse, dim3(128,4), dim3(256), 0, stream,
                       wqC, mem, pe, wkc, bkc, flags, OZ);
  }
  hipLaunchKernelGGL(k_final, dim3(256), dim3(256), 0, stream,
                     OZ, out, flags, sane, detect_ok, (int)(ws_size >> 20));
}

// Round 3
// 4533.383 us; speedup vs baseline: 1.4082x; 1.4067x over previous
//
#include <hip/hip_runtime.h>

// LabelPropagator — low-footprint VALU pipeline (6.27 MB ws).
// Inputs runtime-dtype-detected (f32 vs bf16); OUTPUT = FLOAT32 (ref out dtype).
// Shapes: S=4, c=512, kd=128, P=h*w=1024, F=16 (16384 cross keys), ce=16.
//
// R1/R2: thread-per-query phase B caused unexplained 17.6 GB HBM traffic
//   (identical counters both rounds; duration == traffic/3.7TB/s). Abandoned.
// R3: revert to R0's LDS-tiled phase B (proven 86 MB FETCH) with the two
//   measured problems fixed:
//   (a) bank conflicts (R0: 1.14e9 cyc): Kl bf16 column-rotated 16B granule
//       ((g+row)&15) -> 4-way on the ONE-TIME per-lane K-row load (kept in 16
//       uint4v regs across all 32 tiles); P transposed f32 PlT[j][32] with
//       (q+j)&31 rotation -> <=2-way (free) on both write & read; PE staged
//       [j][16] f32 -> broadcast reads. Q read wave-uniform from global (L1).
//   (b) atomic traffic (R0: 2.7 GB WRITE): OZ partials split into 8 groups by
//       c&7 (bid%8 == c%8 -> same-XCD L2 locality), stored in the dead Y
//       buffer (2.23 MB), reduced in k_final.

typedef __attribute__((ext_vector_type(8))) short short8v;
typedef __attribute__((ext_vector_type(4))) float float4v;
typedef __attribute__((ext_vector_type(4))) unsigned int uint4v;

__device__ __forceinline__ float b2f(unsigned short h){
  union { unsigned int u; float f; } c; c.u = ((unsigned int)h) << 16; return c.f;
}
__device__ __forceinline__ unsigned short f2b(float f){
  union { float f; unsigned int u; } c; c.f = f;
  unsigned int u = c.u;
  u += 0x7fffu + ((u >> 16) & 1u);     // round-to-nearest-even
  return (unsigned short)(u >> 16);
}
// packed-bf16 unpack: low element (bits 15:0) and high element (bits 31:16)
__device__ __forceinline__ float bl(unsigned int u){
  union { unsigned int x; float f; } c; c.x = u << 16; return c.f;
}
__device__ __forceinline__ float bh(unsigned int u){
  union { unsigned int x; float f; } c; c.x = u & 0xffff0000u; return c.f;
}
// flag resolve: fi==-1 forced f32, fi==-2 forced bf16, else flags[fi] (1=f32,0=bf16)
__device__ __forceinline__ int getf(const int* flags, int fi){
  return (fi == -1) ? 1 : ((fi == -2) ? 0 : flags[fi]);
}
__device__ __forceinline__ float ld1(const void* p, long i, int f32f){
  return f32f ? ((const float*)p)[i] : b2f(((const unsigned short*)p)[i]);
}
__device__ __forceinline__ void ld8(const void* p, long i, int f32f, float* o){
  if (f32f){
    float4v a = *(const float4v*)((const float*)p + i);
    float4v b = *(const float4v*)((const float*)p + i + 4);
    o[0]=a[0];o[1]=a[1];o[2]=a[2];o[3]=a[3];o[4]=b[0];o[5]=b[1];o[6]=b[2];o[7]=b[3];
  } else {
    short8v v = *(const short8v*)((const unsigned short*)p + i);
    #pragma unroll
    for (int j=0;j<8;j++) o[j] = b2f((unsigned short)v[j]);
  }
}

// ---------------------------------------------------------------------------
// k_detect: flags[i]=1 if input i is f32 (bf16-exponent>=200 rate > 6.25% over
// first min(n,8192) uint16s; f32-as-bf16 gives ~11%, real bf16 data ~0%).
// ---------------------------------------------------------------------------
__global__ __launch_bounds__(256) void k_detect(
    const void* p0, const void* p1, const void* p2, const void* p3,
    const void* p4, const void* p5, const void* p6,
    int n0, int n1, int n2, int n3, int n4, int n5, int n6,
    int* __restrict__ flags)
{
  const int i = blockIdx.x, t = threadIdx.x;
  const void* ps[7] = {p0,p1,p2,p3,p4,p5,p6};
  int ns[7] = {n0,n1,n2,n3,n4,n5,n6};
  const unsigned short* u = (const unsigned short*)ps[i];
  int n = ns[i]; if (n > 8192) n = 8192;
  int cnt = 0;
  for (int k=t; k<n; k+=256){
    int e = (u[k] >> 7) & 0xFF;
    cnt += (e >= 200) ? 1 : 0;
  }
  __shared__ int red[256];
  red[t] = cnt; __syncthreads();
  for (int off=128; off>0; off>>=1){
    if (t < off) red[t] += red[t+off];
    __syncthreads();
  }
  if (t == 0) flags[i] = (red[0]*16 > n) ? 1 : 0;
}

// ---------------------------------------------------------------------------
// k_proj_g: Out[s][n][128] (bf16) = l2norm(X_token(n) @ W^T + b)
// X layout: [(f*4+s)*512 + ch]*1024 + p, f=n>>10, p=n&1023. Block=128 (d).
// ---------------------------------------------------------------------------
__global__ __launch_bounds__(128) void k_proj_g(
    const void* __restrict__ Xv, int xfi,
    const void* __restrict__ Wv, int wfi,
    const void* __restrict__ Bv, int bfi,
    const int* __restrict__ flags,
    unsigned short* __restrict__ Out, int Ntot)
{
  const int n = blockIdx.x, s = blockIdx.y, d = threadIdx.x;
  const int xf = getf(flags,xfi), wf = getf(flags,wfi), bf = getf(flags,bfi);
  const int f = n >> 10, p = n & 1023;
  const long base = ((long)(f*4 + s) * 512) * 1024 + p;
  float acc = ld1(Bv, d, bf);
  const long wbase = (long)d * 512;
  float wv[8];
  for (int ch=0; ch<512; ch+=8){
    ld8(Wv, wbase + ch, wf, wv);
    #pragma unroll
    for (int j=0;j<8;j++)
      acc += ld1(Xv, base + (long)(ch+j)*1024, xf) * wv[j];
  }
  __shared__ float red[128];
  red[d] = acc*acc;
  __syncthreads();
  for (int off=64; off>0; off>>=1){
    if (d < off) red[d] += red[d+off];
    __syncthreads();
  }
  float r = 1.f / fmaxf(sqrtf(fmaxf(red[0], 0.f)), 1e-12f);
  Out[((long)s*Ntot + n)*128 + d] = f2b(acc * r);
}

// ---------------------------------------------------------------------------
// k_self: per (s,n): fixed-shift softmax over 1024 keys (exp(30d-30), diag
// key => Z>=~1; identical to ref softmax), PV over 512 ch, residual add.
// Y[s][ch][n] (bf16) = tgt + attn.
// ---------------------------------------------------------------------------
__global__ __launch_bounds__(256) void k_self(
    const unsigned short* __restrict__ wq,   // [s][1024][128] bf16 (ws)
    const void* __restrict__ tgt,            // [s][512][1024] flagged
    const int* __restrict__ flags,
    unsigned short* __restrict__ Y)          // [s][512][1024] bf16
{
  const int n = blockIdx.x, s = blockIdx.y, t = threadIdx.x;
  const int tf = flags[0];
  __shared__ float qrow[128];
  __shared__ float ps[1024];
  __shared__ float zred[256];
  if (t < 128) qrow[t] = b2f(wq[((long)s*1024 + n)*128 + t]);
  __syncthreads();
  float zp = 0.f;
  #pragma unroll
  for (int kb=0; kb<4; kb++){
    int k = t + kb*256;
    const unsigned short* kr = wq + ((long)s*1024 + k)*128;
    float dot = 0.f;
    for (int d2=0; d2<128; d2+=8){
      short8v kv = *(const short8v*)(kr + d2);
      #pragma unroll
      for (int j=0;j<8;j++) dot += qrow[d2+j] * b2f((unsigned short)kv[j]);
    }
    float pv = __expf(30.f*dot - 30.f);
    ps[k] = pv; zp += pv;
  }
  zred[t] = zp; __syncthreads();
  for (int off=128; off>0; off>>=1){
    if (t < off) zred[t] += zred[t+off];
    __syncthreads();
  }
  float iz = 1.f / fmaxf(zred[0], 1e-30f);
  float vv[8];
  #pragma unroll
  for (int cb=0; cb<2; cb++){
    int ch = t + cb*256;
    const long vrbase = ((long)s*512 + ch)*1024;
    float acc = 0.f;
    for (int k=0; k<1024; k+=8){
      ld8(tgt, vrbase + k, tf, vv);
      #pragma unroll
      for (int j=0;j<8;j++) acc += ps[k+j] * vv[j];
    }
    Y[vrbase + n] = f2b(ld1(tgt, vrbase + n, tf) + acc*iz);
  }
}

// ---------------------------------------------------------------------------
// k_inorm: in-place InstanceNorm (biased var, eps 1e-5) over 1024 tokens.
// ---------------------------------------------------------------------------
__global__ __launch_bounds__(256) void k_inorm(unsigned short* __restrict__ Y)
{
  const int ch = blockIdx.x, s = blockIdx.y, t = threadIdx.x;
  unsigned short* row = Y + ((long)s*512 + ch)*1024;
  float v[4]; float sum=0.f, ss=0.f;
  #pragma unroll
  for (int i=0;i<4;i++){ v[i]=b2f(row[t+256*i]); sum+=v[i]; ss+=v[i]*v[i]; }
  __shared__ float r1[256], r2[256];
  r1[t]=sum; r2[t]=ss; __syncthreads();
  for (int off=128; off>0; off>>=1){
    if (t<off){ r1[t]+=r1[t+off]; r2[t]+=r2[t+off]; }
    __syncthreads();
  }
  float mean = r1[0]*(1.f/1024.f);
  float var  = fmaxf(r2[0]*(1.f/1024.f) - mean*mean, 0.f);
  float rstd = rsqrtf(var + 1e-5f);
  #pragma unroll
  for (int i=0;i<4;i++) row[t+256*i] = f2b((v[i]-mean)*rstd);
}

// ---------------------------------------------------------------------------
// k_crossfuse (R3): block = (key-chunk c, s); chunk = 128 consecutive keys of
// frame f=c>>3 at p0=(c&7)*128. Partial-group grp=c&7 (same-XCD for all
// blocks of a group since bid%8==c%8 under round-robin dispatch).
//
// Phase A: project + l2norm 128 keys; store bf16 into Kl with COLUMN ROTATION:
//   8-dim group g of key row kk lives at byte kk*256 + ((g+kk)&15)*16.
// Phase A2: PE tile staged as PElp[j][16] f32 (PV reads are broadcasts).
// Phase B: per lane j=t&127, K row loaded ONCE into 16 uint4v regs (rotated
//   addresses, 4-way conflict on this one-time load only). 32 tiles of 32 q:
//   scores thread (j, qg=t>>7): 16 queries, Q read wave-uniform from global;
//   p=exp(30 dot-30) written to PlT[j][ (q+j)&31 ] (f32, <=2-way).
//   PV thread (qh2=t&31, eh=t>>5): e-pair (2eh,2eh+1); reads PlT rotated
//   (conflict-free) + PElp float2 (broadcast); atomicAdd into group partial.
// ---------------------------------------------------------------------------
__global__ __launch_bounds__(256) void k_crossfuse(
    const unsigned short* __restrict__ wqC,  // [s][1024][128] bf16 (ws)
    const void* __restrict__ mem,            // [(f*4+s)*512+ch][1024] flagged
    const void* __restrict__ pe,             // [(f*4+s)*16+e][1024] flagged
    const void* __restrict__ Wv,             // [128][512] flagged
    const void* __restrict__ Bv,             // [128] flagged
    const int* __restrict__ flags,
    float* __restrict__ OZp)                 // [8 grp][4 s][1024][17] f32, zeroed
{
  const int c = blockIdx.x, s = blockIdx.y, t = threadIdx.x;
  const int f = c >> 3, p0 = (c & 7) * 128, grp = c & 7;
  const int mf = flags[1], pf = flags[2], wf = flags[5], bf = flags[6];

  __shared__ unsigned short Kl[128*128];   // 32 KB, column-rotated bf16
  __shared__ float PlT[128*32];            // 16 KB, [j][q-rot] f32
  __shared__ float PElp[128*16];           //  8 KB, [j][e] f32
  __shared__ float ssred[256];

  // ---- Phase A: project + normalize 128 keys (thread = (key kk, dim-half hh))
  const int kk = t & 127, hh = t >> 7;
  {
    float acc[64];
    #pragma unroll
    for (int d=0; d<64; d++) acc[d] = 0.f;
    const long xcol = ((long)(f*4 + s) * 512) * 1024 + p0 + kk;
    for (int ch=0; ch<512; ch+=8){
      float xv[8];
      #pragma unroll
      for (int j=0;j<8;j++) xv[j] = ld1(mem, xcol + (long)(ch+j)*1024, mf);
      #pragma unroll
      for (int d=0; d<64; d++){
        float wv8[8];
        ld8(Wv, (long)(hh*64 + d)*512 + ch, wf, wv8);
        #pragma unroll
        for (int j=0;j<8;j++) acc[d] += xv[j]*wv8[j];
      }
    }
    float ss = 0.f;
    #pragma unroll
    for (int d=0; d<64; d++){
      acc[d] += ld1(Bv, hh*64 + d, bf);
      ss += acc[d]*acc[d];
    }
    ssred[kk*2 + hh] = ss;
    __syncthreads();
    float inv = 1.f / fmaxf(sqrtf(fmaxf(ssred[kk*2] + ssred[kk*2+1], 0.f)), 1e-12f);
    // rotated bf16 stores: 8 x b128, group g at slot (g+kk)&15
    char* krow = (char*)Kl + kk*256;
    #pragma unroll
    for (int gg=0; gg<8; gg++){
      const int g = hh*8 + gg;
      uint4v v;
      #pragma unroll
      for (int w=0; w<4; w++){
        unsigned int lo = f2b(acc[gg*8 + 2*w]   * inv);
        unsigned int hi = f2b(acc[gg*8 + 2*w+1] * inv);
        v[w] = lo | (hi << 16);
      }
      *(uint4v*)(krow + ((g + kk) & 15) * 16) = v;
    }
  }
  // ---- Phase A2: pos_enc tile as PElp[j][16] f32
  #pragma unroll
  for (int i=0;i<8;i++){
    int idx = t*8 + i;            // 0..2047 over [j][e]
    int j2 = idx >> 4, e = idx & 15;
    PElp[j2*16 + e] = ld1(pe, ((long)((f*4 + s)*16 + e))*1024 + p0 + j2, pf);
  }
  __syncthreads();

  // ---- one-time K row load into regs (rotated addresses; static indices)
  const int j = t & 127, qg = t >> 7;
  uint4v kr[16];
  {
    const char* krow = (const char*)Kl + j*256;
    #pragma unroll
    for (int g=0; g<16; g++)
      kr[g] = *(const uint4v*)(krow + ((g + j) & 15) * 16);
  }
  const int qh2 = t & 31, eh = t >> 5;     // PV mapping (8 e-pairs)

  // ---- Phase B: 32 tiles of 32 queries
  for (int qt=0; qt<32; qt++){
    { // scores: thread (j, qg) handles 16 queries
      #pragma unroll
      for (int qi=0; qi<16; qi++){
        const int q = qg*16 + qi;          // 0..31 within tile
        const uint4v* qp = (const uint4v*)(wqC + ((long)s*1024 + qt*32 + q)*128);
        float dot = 0.f;
        #pragma unroll
        for (int g=0; g<16; g++){
          uint4v qv = qp[g];               // wave-uniform global read (L1)
          #pragma unroll
          for (int w=0; w<4; w++){
            dot += bl(qv[w])*bl(kr[g][w]) + bh(qv[w])*bh(kr[g][w]);
          }
        }
        PlT[j*32 + ((q + j) & 31)] = __expf(30.f*dot - 30.f);
      }
    }
    __syncthreads();
    { // PV: thread (qh2, eh) -> e-pair (2eh, 2eh+1)
      float O0 = 0.f, O1 = 0.f, z = 0.f;
      #pragma unroll 4
      for (int j2=0; j2<128; j2++){
        float p = PlT[j2*32 + ((qh2 + j2) & 31)];
        const float* pep = &PElp[j2*16 + eh*2];
        O0 += p * pep[0];
        O1 += p * pep[1];
        z  += p;
      }
      float* oz = OZp + ((((long)grp*4 + s)*1024) + qt*32 + qh2)*17;
      atomicAdd(&oz[2*eh],   O0);
      atomicAdd(&oz[2*eh+1], O1);
      if (eh == 0) atomicAdd(&oz[16], z);
    }
    __syncthreads();
  }
}

// ---------------------------------------------------------------------------
// k_final: out (FLOAT32) = sigmoid(O/Z) summing 8 group partials; diagnostic
// if ws too small. out[i], i = ((s*16+e)<<10)+n.
// ---------------------------------------------------------------------------
__global__ __launch_bounds__(256) void k_final(
    const float* __restrict__ OZp, float* __restrict__ out,
    const int* __restrict__ flags, int sane, int detect_ok, int ws_mb)
{
  const int i = blockIdx.x*256 + threadIdx.x;   // 0..65535
  if (!sane){
    float v = 0.5f;
    if (i == 0){
      int F = 0;
      if (detect_ok)
        F = flags[0]*16 + flags[1]*8 + flags[2]*4 + flags[3]*2 + flags[5];
      int wm = ws_mb > 99 ? 99 : ws_mb;
      v = ldexpf(1.f + (float)wm*(1.f/128.f), 40 + F);
    }
    out[i] = v;
    return;
  }
  const int s = i >> 14, e = (i >> 10) & 15, n = i & 1023;
  float x = 0.f, z = 0.f;
  #pragma unroll
  for (int g=0; g<8; g++){
    const float* oz = OZp + (((long)g*4 + s)*1024 + n)*17;
    x += oz[e];
    z += oz[16];
  }
  float r = x / fmaxf(z, 1e-30f);
  out[i] = 1.f / (1.f + __expf(-r));
}

// ---------------------------------------------------------------------------
extern "C" void kernel_launch(void* const* d_in, const int* in_sizes, int n_in,
                              void* d_out, int out_size, void* d_ws, size_t ws_size,
                              hipStream_t stream)
{
  const void* tgt = d_in[0];
  const void* mem = d_in[1];
  const void* pe  = d_in[2];
  const void* wks = d_in[3];
  const void* bks = d_in[4];
  const void* wkc = d_in[5];
  const void* bkc = d_in[6];
  float* out = (float*)d_out;   // [4][16][1024] FLOAT32 (reference output dtype)

  char* w = (char*)d_ws;
  int*            flags = (int*)w;          w += 256;
  unsigned short* wqS = (unsigned short*)w; w += (size_t)4*1024*128*2;   // 1 MB
  unsigned short* wqC = (unsigned short*)w; w += (size_t)4*1024*128*2;   // 1 MB
  unsigned short* Y   = (unsigned short*)w; w += (size_t)4*512*1024*2;   // 4 MB
  float*          OZ  = (float*)w;          w += (size_t)4*1024*17*4;    // 272 KB
  const size_t NEED = (size_t)(w - (char*)d_ws);

  // OZ partials (8 groups) live in the dead Y buffer during k_crossfuse.
  float* OZp = (float*)Y;                   // 8*4*1024*17*4 = 2228224 B <= 4 MB

  const int detect_ok = ws_size >= 4096;
  const int sane = ws_size >= NEED;

  if (detect_ok)
    hipLaunchKernelGGL(k_detect, dim3(7), dim3(256), 0, stream,
                       tgt, mem, pe, wks, bks, wkc, bkc,
                       in_sizes[0], in_sizes[1], in_sizes[2], in_sizes[3],
                       in_sizes[4], in_sizes[5], in_sizes[6], flags);
  if (sane){
    hipLaunchKernelGGL(k_proj_g, dim3(1024,4), dim3(128), 0, stream,
                       tgt, 0, wks, 3, bks, 4, flags, wqS, 1024);
    hipLaunchKernelGGL(k_self, dim3(1024,4), dim3(256), 0, stream,
                       wqS, tgt, flags, Y);
    hipLaunchKernelGGL(k_inorm, dim3(512,4), dim3(256), 0, stream, Y);
    hipLaunchKernelGGL(k_proj_g, dim3(1024,4), dim3(128), 0, stream,
                       (const void*)Y, -2, wkc, 5, bkc, 6, flags, wqC, 1024);
    // Y is dead from here: reuse as OZ partial buffer.
    hipMemsetAsync(OZp, 0, (size_t)8*4*1024*17*4, stream);
    hipLaunchKernelGGL(k_crossfuse, dim3(128,4), dim3(256), 0, stream,
                       wqC, mem, pe, wkc, bkc, flags, OZp);
  }
  hipLaunchKernelGGL(k_final, dim3(256), dim3(256), 0, stream,
                     (const float*)OZp, out, flags, sane, detect_ok,
                     (int)(ws_size >> 20));
}